// Round 4
// baseline (124.955 us; speedup 1.0000x reference)
//
#include <hip/hip_runtime.h>
#include <math.h>

// FedTGPClientLoss: fused CE (log-softmax gather) + prototype-MSE.
// B=16384, C=1000, D=512.
// R7 design: two kernels. Rows kernel now SOFTWARE-PIPELINED: each wave owns
// 4 consecutive rows, prefetches all 4 labels up front, and double-buffers
// the 8 vector loads (4 logit float4 + 2 feature + 2 proto) so row r+1's
// loads are in flight while row r's exp/butterfly tail executes. This keeps
// the memory pipe busy through the compute tails that left R6 at ~28us vs
// the ~17us memory floor. Per-row math identical to R6 (bitwise-same output).
// Note: C=1000 floats = 250 float4 exactly -> all rows 16B-aligned.

#ifndef INFINITY
#define INFINITY __builtin_inff()
#endif

__device__ __forceinline__ float safe_exp(float dm) {
    // exp(min(dm,0)): dm <= 0 mathematically; fmin also flushes the NaN from
    // (-inf) - (-inf) on fully-padded lanes to 0 -> exp=1 paired with s=0.
    return __expf(fminf(dm, 0.0f));
}

#define RPW 4   // rows per wave

__global__ __launch_bounds__(256) void fedtgp_rows(
    const float* __restrict__ logits,
    const int*   __restrict__ labels,
    const float* __restrict__ features,
    const float* __restrict__ protos,
    float2* __restrict__ part,          // per-row (ce, pl)
    int B, int C, int D)
{
    const int tid  = threadIdx.x;
    const int lane = tid & 63;
    const int wv   = tid >> 6;
    const int wave = blockIdx.x * 4 + wv;
    const int base = wave * RPW;
    if (base >= B) return;

    const int C4 = C >> 2;
    const int D4 = D >> 2;

    const bool fast = (base + RPW <= B) &&
                      (C4 >= 64 && C4 <= 256 && D4 >= 64 && D4 <= 128 &&
                       (C & 3) == 0 && (D & 3) == 0);

    if (fast) {
        // ---- fast path for benchmarked shape (C=1000, D=512) ----
        int labs[RPW];
        #pragma unroll
        for (int r = 0; r < RPW; ++r) labs[r] = labels[base + r];

        float4 v[2][4], f[2][2], p[2][2];   // double-buffered load sets
        float ll[RPW];

        const int i1 = min(lane + 64,  C4 - 1);
        const int i2 = min(lane + 128, C4 - 1);
        const int i3 = min(lane + 192, C4 - 1);
        const int j1 = min(lane + 64,  D4 - 1);
        const bool b1 = (lane + 64  < C4);
        const bool b2 = (lane + 128 < C4);
        const bool b3 = (lane + 192 < C4);
        const bool d1 = (lane + 64  < D4);

// Issue all 9 loads for row RR into buffer BUF (BUF is a literal 0/1 so all
// array indexing is compile-time -> registers, not scratch).
#define ISSUE(BUF, RR)                                                        \
        {                                                                     \
            const int row_ = base + (RR);                                     \
            const float* lrow_ = logits + (size_t)row_ * C;                   \
            const float4* l4_ = (const float4*)lrow_;                         \
            const float4* f4_ = (const float4*)(features + (size_t)row_ * D); \
            const float4* p4_ = (const float4*)(protos + (size_t)labs[RR] * D);\
            v[BUF][0] = l4_[lane];                                            \
            v[BUF][1] = l4_[i1];                                              \
            v[BUF][2] = l4_[i2];                                              \
            v[BUF][3] = l4_[i3];                                              \
            f[BUF][0] = f4_[lane];  f[BUF][1] = f4_[j1];                      \
            p[BUF][0] = p4_[lane];  p[BUF][1] = p4_[j1];                      \
            ll[RR] = lrow_[labs[RR]];                                         \
        }

#define COMPUTE(BUF, RR)                                                      \
        {                                                                     \
            const float NI = -INFINITY;                                       \
            float4 w1 = v[BUF][1], w2 = v[BUF][2], w3 = v[BUF][3];            \
            w1.x = b1 ? w1.x : NI; w1.y = b1 ? w1.y : NI;                     \
            w1.z = b1 ? w1.z : NI; w1.w = b1 ? w1.w : NI;                     \
            w2.x = b2 ? w2.x : NI; w2.y = b2 ? w2.y : NI;                     \
            w2.z = b2 ? w2.z : NI; w2.w = b2 ? w2.w : NI;                     \
            w3.x = b3 ? w3.x : NI; w3.y = b3 ? w3.y : NI;                     \
            w3.z = b3 ? w3.z : NI; w3.w = b3 ? w3.w : NI;                     \
            const float4 w0 = v[BUF][0];                                      \
            float m = fmaxf(fmaxf(fmaxf(w0.x, w0.y), fmaxf(w0.z, w0.w)),      \
                            fmaxf(fmaxf(w1.x, w1.y), fmaxf(w1.z, w1.w)));     \
            m = fmaxf(m, fmaxf(fmaxf(w2.x, w2.y), fmaxf(w2.z, w2.w)));        \
            m = fmaxf(m, fmaxf(fmaxf(w3.x, w3.y), fmaxf(w3.z, w3.w)));        \
            float s = safe_exp(w0.x - m) + safe_exp(w0.y - m)                 \
                    + safe_exp(w0.z - m) + safe_exp(w0.w - m);                \
            s += safe_exp(w1.x - m) + safe_exp(w1.y - m)                      \
               + safe_exp(w1.z - m) + safe_exp(w1.w - m);                     \
            s += safe_exp(w2.x - m) + safe_exp(w2.y - m)                      \
               + safe_exp(w2.z - m) + safe_exp(w2.w - m);                     \
            s += safe_exp(w3.x - m) + safe_exp(w3.y - m)                      \
               + safe_exp(w3.z - m) + safe_exp(w3.w - m);                     \
            float dx = f[BUF][0].x - p[BUF][0].x;                             \
            float dy = f[BUF][0].y - p[BUF][0].y;                             \
            float dz = f[BUF][0].z - p[BUF][0].z;                             \
            float dw = f[BUF][0].w - p[BUF][0].w;                             \
            float q = dx*dx + dy*dy + dz*dz + dw*dw;                          \
            dx = f[BUF][1].x - p[BUF][1].x; dy = f[BUF][1].y - p[BUF][1].y;   \
            dz = f[BUF][1].z - p[BUF][1].z; dw = f[BUF][1].w - p[BUF][1].w;   \
            const float q1 = dx*dx + dy*dy + dz*dz + dw*dw;                   \
            q += d1 ? q1 : 0.0f;                                              \
            float M = m;                                                      \
            _Pragma("unroll")                                                 \
            for (int off = 32; off > 0; off >>= 1)                            \
                M = fmaxf(M, __shfl_xor(M, off, 64));                         \
            s *= safe_exp(m - M);                                             \
            _Pragma("unroll")                                                 \
            for (int off = 32; off > 0; off >>= 1) {                          \
                s += __shfl_xor(s, off, 64);                                  \
                q += __shfl_xor(q, off, 64);                                  \
            }                                                                 \
            if (lane == 0)                                                    \
                part[base + (RR)] = make_float2((M + __logf(s)) - ll[RR],     \
                                                q / (float)D);                \
        }

        // pipeline: two rows' loads in flight at steady state
        ISSUE(0, 0);
        ISSUE(1, 1);
        COMPUTE(0, 0);
        ISSUE(0, 2);
        COMPUTE(1, 1);
        ISSUE(1, 3);
        COMPUTE(0, 2);
        COMPUTE(1, 3);
#undef ISSUE
#undef COMPUTE
    } else {
        // ---- generic fallback (correctness only; not hit for bench shape) --
        for (int r = 0; r < RPW; ++r) {
            const int row = base + r;
            if (row >= B) break;
            const int lab = labels[row];
            const float* lrow = logits + (size_t)row * C;
            float m = -INFINITY, s = 0.f, q = 0.f;
            for (int c = lane; c < C; c += 64) {
                const float x  = lrow[c];
                const float cm = fmaxf(m, x);
                s = s * safe_exp(m - cm) + safe_exp(x - cm);
                m = cm;
            }
            for (int d = lane; d < D; d += 64) {
                const float df = features[(size_t)row * D + d]
                               - protos[(size_t)lab * D + d];
                q += df * df;
            }
            const float ll2 = lrow[lab];
            #pragma unroll
            for (int off = 32; off > 0; off >>= 1) {
                const float om = __shfl_xor(m, off, 64);
                const float os = __shfl_xor(s, off, 64);
                q += __shfl_xor(q, off, 64);
                const float nm = fmaxf(m, om);
                s = s * safe_exp(m - nm) + os * safe_exp(om - nm);
                m = nm;
            }
            if (lane == 0)
                part[row] = make_float2((m + __logf(s)) - ll2, q / (float)D);
        }
    }
}

__global__ __launch_bounds__(1024) void fedtgp_finalize(
    const float2* __restrict__ part,
    float* __restrict__ out,
    int B, double invB)
{
    const int tid  = threadIdx.x;
    const int lane = tid & 63;
    const int wv   = tid >> 6;
    __shared__ double rc[16];
    __shared__ double rp[16];

    double c = 0.0, p = 0.0;
    for (int i = tid; i < B; i += 1024) {
        const float2 v = part[i];
        c += (double)v.x;
        p += (double)v.y;
    }
    #pragma unroll
    for (int off = 32; off > 0; off >>= 1) {
        c += __shfl_xor(c, off, 64);
        p += __shfl_xor(p, off, 64);
    }
    if (lane == 0) { rc[wv] = c; rp[wv] = p; }
    __syncthreads();

    if (tid == 0) {
        double cs = 0.0, ps = 0.0;
        #pragma unroll
        for (int k = 0; k < 16; ++k) { cs += rc[k]; ps += rp[k]; }
        float ce = (float)(cs * invB);
        float pl = (float)(ps * invB);
        if (!isfinite(ce)) ce = 0.0f;          // ce_loss = where(isfinite, ce, 0)
        float tot = ce + pl;                   // LAMDA = 1.0
        if (!isfinite(tot)) tot = ce;          // total = where(isfinite, total, ce)
        out[0] = tot;
        out[1] = ce;
        out[2] = pl;
    }
}

extern "C" void kernel_launch(void* const* d_in, const int* in_sizes, int n_in,
                              void* d_out, int out_size, void* d_ws, size_t ws_size,
                              hipStream_t stream)
{
    const float* logits   = (const float*)d_in[0];
    const int*   labels   = (const int*)  d_in[1];
    const float* features = (const float*)d_in[2];
    const float* protos   = (const float*)d_in[3];
    float* out = (float*)d_out;

    const int B = in_sizes[1];              // 16384
    const int C = in_sizes[0] / B;          // 1000
    const int D = in_sizes[2] / B;          // 512

    float2* part = (float2*)d_ws;           // B * 8 bytes = 128 KB << ws_size

    const int waves = (B + RPW - 1) / RPW;  // 4096 waves, 4 rows each
    const int nb = (waves + 3) / 4;         // 4 waves/block -> 1024 blocks
    fedtgp_rows<<<nb, 256, 0, stream>>>(logits, labels, features, protos,
                                        part, B, C, D);
    fedtgp_finalize<<<1, 1024, 0, stream>>>(part, out, B, 1.0 / (double)B);
}